// Round 6
// baseline (77.334 us; speedup 1.0000x reference)
//
#include <hip/hip_runtime.h>
#include <math.h>

#define BB 16
#define HH 256
#define WW 256
#define NPIX (BB*HH*WW)
#define CH 16          // 16-row chunks per column
#define RPC 16
#define ROWS 8         // rows per rowmin block
#define NRB (BB*HH/ROWS)       // 512 rowmin blocks
#define PADW 4
#define GSTRIDE (WW + 2*PADW)  // 264 floats

// ws layout:
//   ushort zb[BB*CH*WW]     (128 KB)  bit r of zb[b,c,j] = (targ[b, c*16+r, j] == 0)
//   float  partials[NRB*8]  (16 KB)   per-block {sp,st,spt,sbce,sphip,amax,anym,pad}
//   unsigned done[16]       (64 B)    completion counter (own cacheline)

// targ -> zero bitmasks. 256 blocks (one 16-row chunk) x 64 threads (4 cols each).
// Block 0 also zeroes the done-counter (visible to rowmin via kernel boundary).
__global__ __launch_bounds__(64) void zbuild_kernel(const float4* __restrict__ targ4,
                                                    ushort4* __restrict__ zb4,
                                                    unsigned* __restrict__ done) {
    if (blockIdx.x == 0 && threadIdx.x == 0) done[0] = 0u;
    int blk = blockIdx.x;                 // b*16 + ch ; row offset = blk*16
    int t = threadIdx.x;
    const float4* m = targ4 + (size_t)blk * RPC * (WW / 4) + t;
    unsigned z0 = 0, z1 = 0, z2 = 0, z3 = 0;
    #pragma unroll
    for (int r = 0; r < RPC; ++r) {
        float4 v = m[r * (WW / 4)];
        if (v.x == 0.0f) z0 |= 1u << r;
        if (v.y == 0.0f) z1 |= 1u << r;
        if (v.z == 0.0f) z2 |= 1u << r;
        if (v.w == 0.0f) z3 |= 1u << r;
    }
    ushort4 o;
    o.x = (unsigned short)z0; o.y = (unsigned short)z1;
    o.z = (unsigned short)z2; o.w = (unsigned short)z3;
    zb4[blk * (WW / 4) + t] = o;
}

// Fused EDT pass2 + loss partials + last-block final reduction.
__global__ __launch_bounds__(256) void rowmin_fused_kernel(const unsigned short* __restrict__ zb,
                                                           const float* __restrict__ pred,
                                                           float* __restrict__ partials,
                                                           unsigned* __restrict__ done,
                                                           float* __restrict__ out) {
    int g = blockIdx.x;
    int b = g >> 5;                 // 32 blocks per image
    int r0 = (g & 31) << 3;         // first row-in-image (multiple of 8)
    int C = r0 >> 4;                // chunk containing all 8 rows
    int rb0 = r0 & 15;
    int j = threadIdx.x;

    // stream 16 chunk masks: carries + own-chunk mask, no indexed register array
    int la0 = -1, la1 = -1;         // last zero strictly above chunk C (flavor 0/1)
    int fb0 = 100000, fb1 = 100000; // first zero strictly below chunk C
    unsigned zoc = 0;
    int anym = 0;
    #pragma unroll
    for (int c = 0; c < CH; ++c) {
        unsigned z = (unsigned)zb[((b * CH + c) << 8) + j];
        unsigned zi = (~z) & 0xFFFFu;
        anym |= (zi != 0u);
        if (c < C) {
            if (z)  la0 = (c << 4) + (31 - __clz(z));
            if (zi) la1 = (c << 4) + (31 - __clz(zi));
        } else if (c > C) {
            if (z  && fb0 == 100000) fb0 = (c << 4) + (__ffs(z) - 1);
            if (zi && fb1 == 100000) fb1 = (c << 4) + (__ffs(zi) - 1);
        } else {
            zoc = z;
        }
    }
    unsigned zoc1 = (~zoc) & 0xFFFFu;

    float x[ROWS];
    #pragma unroll
    for (int r = 0; r < ROWS; ++r)
        x[r] = pred[(((b << 8) + (r0 + r)) << 8) + j];

    __shared__ float gg[ROWS][2][GSTRIDE];   // [0,4) pad | data [4,260) | [260,264) pad
    if (j < 2 * ROWS * 2 * PADW) {           // 128 pad slots
        int r = j >> 4, f = (j >> 3) & 1, p = j & 7;
        gg[r][f][(p < PADW) ? p : (WW + p)] = 1e30f;
    }

    #pragma unroll
    for (int r = 0; r < ROWS; ++r) {
        int rb = rb0 + r;
        int i = r0 + r;
        unsigned below = zoc & ((2u << rb) - 1u);
        int lz = below ? ((C << 4) + (31 - __clz(below))) : la0;
        unsigned above = zoc & (0xFFFFu & ~((1u << rb) - 1u));
        int fz = above ? ((C << 4) + (__ffs(above) - 1)) : fb0;
        int da = (lz < 0) ? 100000 : (i - lz);
        int d0 = min(min(da, fz - i), 512);
        float f0 = (float)d0;
        gg[r][0][PADW + j] = f0 * f0;
        unsigned below1 = zoc1 & ((2u << rb) - 1u);
        int lz1 = below1 ? ((C << 4) + (31 - __clz(below1))) : la1;
        unsigned above1 = zoc1 & (0xFFFFu & ~((1u << rb) - 1u));
        int fz1 = above1 ? ((C << 4) + (__ffs(above1) - 1)) : fb1;
        int da1 = (lz1 < 0) ? 100000 : (i - lz1);
        int d1v = min(min(da1, fz1 - i), 512);
        float f1 = (float)d1v;
        gg[r][1][PADW + j] = f1 * f1;
    }
    __syncthreads();

    float sp = 0.f, st = 0.f, spt = 0.f, sbce = 0.f, sphip = 0.f, amax = 0.f;
    #pragma unroll
    for (int r = 0; r < ROWS; ++r) {
        int rb = rb0 + r;
        bool msk = (((zoc >> rb) & 1u) == 0u);    // mask nonzero at this pixel
        const float* bsel = &gg[r][msk ? 0 : 1][0];
        float best = 1e30f;
        #pragma unroll
        for (int c = 0; c <= 2 * PADW; ++c) {
            float Cc = (float)((PADW - c) * (PADW - c));   // == (j-k)^2, k = j-4+c
            best = fminf(best, bsel[j + c] + Cc);
        }
        if (__any(best > 25.0f)) {                // exact fallback (astronomically rare)
            const float* bs = bsel + PADW;
            for (int k = 0; k < WW; ++k) {
                float df = (float)(j - k);
                best = fminf(best, bs[k] + df * df);
            }
        }
        float dd = sqrtf(best);
        float phi = msk ? -dd : dd;               // phi = dist_out - dist_in
        float xr = x[r];
        float ax = fabsf(xr);
        float q = __expf(-ax);
        float pa = 1.0f / (1.0f + q);             // sigmoid(|x|)
        float p = (xr >= 0.0f) ? pa : q * pa;     // sigmoid(x)
        sp += p;
        st += msk ? 1.0f : 0.0f;
        spt += msk ? p : 0.0f;
        sbce += fmaxf(xr, 0.0f) - (msk ? xr : 0.0f) - __logf(pa);  // log1p(e^-|x|) = -log(pa)
        sphip += phi * p;
        amax = fmaxf(amax, fabsf(phi));
    }

    float anymf = (float)anym;
    #pragma unroll
    for (int off = 32; off > 0; off >>= 1) {
        sp    += __shfl_down(sp,    off, 64);
        st    += __shfl_down(st,    off, 64);
        spt   += __shfl_down(spt,   off, 64);
        sbce  += __shfl_down(sbce,  off, 64);
        sphip += __shfl_down(sphip, off, 64);
        amax   = fmaxf(amax,  __shfl_down(amax,  off, 64));
        anymf  = fmaxf(anymf, __shfl_down(anymf, off, 64));
    }
    __shared__ float red[4][8];
    int lane = j & 63, wv = j >> 6;
    if (lane == 0) {
        red[wv][0] = sp; red[wv][1] = st; red[wv][2] = spt; red[wv][3] = sbce;
        red[wv][4] = sphip; red[wv][5] = amax; red[wv][6] = anymf;
    }
    __syncthreads();
    __shared__ int lastflag;
    if (j == 0) {
        float* o = partials + g * 8;
        #pragma unroll
        for (int q2 = 0; q2 < 5; ++q2)
            o[q2] = red[0][q2] + red[1][q2] + red[2][q2] + red[3][q2];
        o[5] = fmaxf(fmaxf(red[0][5], red[1][5]), fmaxf(red[2][5], red[3][5]));
        o[6] = fmaxf(fmaxf(red[0][6], red[1][6]), fmaxf(red[2][6], red[3][6]));
        __threadfence();                           // publish partials (device scope)
        unsigned old = atomicAdd(done, 1u);
        lastflag = (old == (unsigned)(NRB - 1));
    }
    __syncthreads();
    if (!lastflag) return;
    __threadfence();                               // acquire all partials

    // ---- final reduction (last block only) ----
    int t = j;
    float s0 = 0.f, s1 = 0.f, s2 = 0.f, s3 = 0.f, s4 = 0.f, m5 = 0.f, a6 = 0.f;
    #pragma unroll
    for (int e = 0; e < 2; ++e) {                  // records 2t, 2t+1: both image t>>4
        const float* rec = partials + ((t * 2 + e) << 3);
        s0 += rec[0]; s1 += rec[1]; s2 += rec[2]; s3 += rec[3];
        s4 += rec[4];
        m5 = fmaxf(m5, rec[5]);
        a6 = fmaxf(a6, rec[6]);
    }
    __shared__ float arr[256][3];
    arr[t][0] = s4; arr[t][1] = m5; arr[t][2] = a6;
    __syncthreads();
    __shared__ float bnd[16];
    if (t < 16) {
        float Sb = 0.f, Mb = 0.f, Ab = 0.f;
        for (int e = 0; e < 16; ++e) {
            Sb += arr[t * 16 + e][0];
            Mb = fmaxf(Mb, arr[t * 16 + e][1]);
            Ab = fmaxf(Ab, arr[t * 16 + e][2]);
        }
        bnd[t] = (Ab != 0.0f) ? (Sb / (Mb + 1e-8f)) : 0.0f;
    }
    #pragma unroll
    for (int off = 32; off > 0; off >>= 1) {
        s0 += __shfl_down(s0, off, 64);
        s1 += __shfl_down(s1, off, 64);
        s2 += __shfl_down(s2, off, 64);
        s3 += __shfl_down(s3, off, 64);
    }
    __shared__ float wred[4][4];
    if (lane == 0) { wred[wv][0] = s0; wred[wv][1] = s1; wred[wv][2] = s2; wred[wv][3] = s3; }
    __syncthreads();
    if (t == 0) {
        float spF   = wred[0][0] + wred[1][0] + wred[2][0] + wred[3][0];
        float stF   = wred[0][1] + wred[1][1] + wred[2][1] + wred[3][1];
        float sptF  = wred[0][2] + wred[1][2] + wred[2][2] + wred[3][2];
        float sbceF = wred[0][3] + wred[1][3] + wred[2][3] + wred[3][3];
        float sbnd = 0.f;
        #pragma unroll
        for (int bb2 = 0; bb2 < BB; ++bb2) sbnd += bnd[bb2];
        float dice = 1.0f - (2.0f * sptF + 1e-6f) / (spF + stF + 1e-6f);
        float invN = 1.0f / (float)NPIX;
        float boundary = sbnd * invN;
        float bce = sbceF * invN;
        float alpha = 0.005f;
        float beta = 0.6f - alpha;      // 0.595
        out[0] = (1.0f - beta) * dice + beta * boundary + 0.4f * bce;
    }
}

extern "C" void kernel_launch(void* const* d_in, const int* in_sizes, int n_in,
                              void* d_out, int out_size, void* d_ws, size_t ws_size,
                              hipStream_t stream) {
    (void)in_sizes; (void)n_in; (void)out_size; (void)ws_size;
    const float* pred = (const float*)d_in[0];
    const float* targ = (const float*)d_in[1];
    unsigned short* zb = (unsigned short*)d_ws;                      // 128 KB
    float* partials = (float*)((char*)d_ws + BB * CH * WW * sizeof(unsigned short));
    unsigned* done = (unsigned*)(partials + NRB * 8);                // own line

    zbuild_kernel<<<BB * CH, 64, 0, stream>>>((const float4*)targ, (ushort4*)zb, done);
    rowmin_fused_kernel<<<NRB, 256, 0, stream>>>(zb, pred, partials, done, (float*)d_out);
}

// Round 7
// 70.904 us; speedup vs baseline: 1.0907x; 1.0907x over previous
//
#include <hip/hip_runtime.h>
#include <math.h>

#define BB 16
#define HH 256
#define WW 256
#define NPIX (BB*HH*WW)
#define CH 16          // 16-row chunks per column
#define RPC 16
#define ROWS 8         // rows per rowmin block
#define NRB (BB*HH/ROWS)       // 512 rowmin blocks
#define PADW 4
#define GSTRIDE (WW + 2*PADW)  // 264 floats

// ws layout:
//   ushort zb[BB*CH*WW]   (128 KB)  bit r of zb[b,c,j] = (targ[b, c*16+r, j] == 0)
//   float  partials[NRB*8] (16 KB)  per-block {sp,st,spt,sbce,sphip,amax,-,-}

// targ -> zero bitmasks. 256 blocks (one 16-row chunk) x 64 threads (4 cols each).
__global__ __launch_bounds__(64) void zbuild_kernel(const float4* __restrict__ targ4,
                                                    ushort4* __restrict__ zb4) {
    int blk = blockIdx.x;                 // b*16 + ch ; row offset = blk*16
    int t = threadIdx.x;
    const float4* m = targ4 + (size_t)blk * RPC * (WW / 4) + t;
    unsigned z0 = 0, z1 = 0, z2 = 0, z3 = 0;
    #pragma unroll
    for (int r = 0; r < RPC; ++r) {
        float4 v = m[r * (WW / 4)];
        if (v.x == 0.0f) z0 |= 1u << r;
        if (v.y == 0.0f) z1 |= 1u << r;
        if (v.z == 0.0f) z2 |= 1u << r;
        if (v.w == 0.0f) z3 |= 1u << r;
    }
    ushort4 o;
    o.x = (unsigned short)z0; o.y = (unsigned short)z1;
    o.z = (unsigned short)z2; o.w = (unsigned short)z3;
    zb4[blk * (WW / 4) + t] = o;
}

// Fused EDT pass2 + loss partials. One block per 8 rows (within one chunk).
// Column-EDT derived in-register from streamed bitmasks; windowed exact min
// (|j-k|<=4, bound 25: any k outside contributes >= 25, all values exact ints
// in fp32) with per-wave full-scan fallback for worst-case exactness.
__global__ __launch_bounds__(256) void rowmin_fused_kernel(const unsigned short* __restrict__ zb,
                                                           const float* __restrict__ pred,
                                                           float* __restrict__ partials) {
    int g = blockIdx.x;
    int b = g >> 5;                 // 32 blocks per image
    int r0 = (g & 31) << 3;         // first row-in-image (multiple of 8)
    int C = r0 >> 4;                // chunk containing all 8 rows
    int rb0 = r0 & 15;
    int j = threadIdx.x;

    // stream 16 chunk masks: carries + own-chunk mask, no indexed register array
    int la0 = -1, la1 = -1;         // last zero strictly above chunk C (flavor 0/1)
    int fb0 = 100000, fb1 = 100000; // first zero strictly below chunk C
    unsigned zoc = 0;
    #pragma unroll
    for (int c = 0; c < CH; ++c) {
        unsigned z = (unsigned)zb[((b * CH + c) << 8) + j];
        unsigned zi = (~z) & 0xFFFFu;
        if (c < C) {
            if (z)  la0 = (c << 4) + (31 - __clz(z));
            if (zi) la1 = (c << 4) + (31 - __clz(zi));
        } else if (c > C) {
            if (z  && fb0 == 100000) fb0 = (c << 4) + (__ffs(z) - 1);
            if (zi && fb1 == 100000) fb1 = (c << 4) + (__ffs(zi) - 1);
        } else {
            zoc = z;
        }
    }
    unsigned zoc1 = (~zoc) & 0xFFFFu;

    float x[ROWS];
    #pragma unroll
    for (int r = 0; r < ROWS; ++r)
        x[r] = pred[(((b << 8) + (r0 + r)) << 8) + j];

    __shared__ float gg[ROWS][2][GSTRIDE];   // [0,4) pad | data [4,260) | [260,264) pad
    if (j < 2 * ROWS * 2 * PADW) {           // 128 pad slots
        int r = j >> 4, f = (j >> 3) & 1, p = j & 7;
        gg[r][f][(p < PADW) ? p : (WW + p)] = 1e30f;
    }

    #pragma unroll
    for (int r = 0; r < ROWS; ++r) {
        int rb = rb0 + r;
        int i = r0 + r;
        unsigned below = zoc & ((2u << rb) - 1u);
        int lz = below ? ((C << 4) + (31 - __clz(below))) : la0;
        unsigned above = zoc & (0xFFFFu & ~((1u << rb) - 1u));
        int fz = above ? ((C << 4) + (__ffs(above) - 1)) : fb0;
        int da = (lz < 0) ? 100000 : (i - lz);
        int d0 = min(min(da, fz - i), 512);
        float f0 = (float)d0;
        gg[r][0][PADW + j] = f0 * f0;
        unsigned below1 = zoc1 & ((2u << rb) - 1u);
        int lz1 = below1 ? ((C << 4) + (31 - __clz(below1))) : la1;
        unsigned above1 = zoc1 & (0xFFFFu & ~((1u << rb) - 1u));
        int fz1 = above1 ? ((C << 4) + (__ffs(above1) - 1)) : fb1;
        int da1 = (lz1 < 0) ? 100000 : (i - lz1);
        int d1v = min(min(da1, fz1 - i), 512);
        float f1 = (float)d1v;
        gg[r][1][PADW + j] = f1 * f1;
    }
    __syncthreads();

    float sp = 0.f, st = 0.f, spt = 0.f, sbce = 0.f, sphip = 0.f, amax = 0.f;
    #pragma unroll
    for (int r = 0; r < ROWS; ++r) {
        int rb = rb0 + r;
        bool msk = (((zoc >> rb) & 1u) == 0u);    // mask nonzero at this pixel
        const float* bsel = &gg[r][msk ? 0 : 1][0];
        float best = 1e30f;
        #pragma unroll
        for (int c = 0; c <= 2 * PADW; ++c) {
            float Cc = (float)((PADW - c) * (PADW - c));   // == (j-k)^2, k = j-4+c
            best = fminf(best, bsel[j + c] + Cc);
        }
        if (__any(best > 25.0f)) {                // exact fallback (astronomically rare)
            const float* bs = bsel + PADW;
            for (int k = 0; k < WW; ++k) {
                float df = (float)(j - k);
                best = fminf(best, bs[k] + df * df);
            }
        }
        float dd = sqrtf(best);
        float phi = msk ? -dd : dd;               // phi = dist_out - dist_in
        float xr = x[r];
        float ax = fabsf(xr);
        float q = __expf(-ax);
        float pa = 1.0f / (1.0f + q);             // sigmoid(|x|)
        float p = (xr >= 0.0f) ? pa : q * pa;     // sigmoid(x)
        sp += p;
        st += msk ? 1.0f : 0.0f;
        spt += msk ? p : 0.0f;
        sbce += fmaxf(xr, 0.0f) - (msk ? xr : 0.0f) - __logf(pa);  // log1p(e^-|x|) = -log(pa)
        sphip += phi * p;
        amax = fmaxf(amax, fabsf(phi));
    }

    #pragma unroll
    for (int off = 32; off > 0; off >>= 1) {
        sp    += __shfl_down(sp,    off, 64);
        st    += __shfl_down(st,    off, 64);
        spt   += __shfl_down(spt,   off, 64);
        sbce  += __shfl_down(sbce,  off, 64);
        sphip += __shfl_down(sphip, off, 64);
        amax   = fmaxf(amax,  __shfl_down(amax,  off, 64));
    }
    __shared__ float red[4][8];
    int lane = j & 63, wv = j >> 6;
    if (lane == 0) {
        red[wv][0] = sp; red[wv][1] = st; red[wv][2] = spt; red[wv][3] = sbce;
        red[wv][4] = sphip; red[wv][5] = amax;
    }
    __syncthreads();
    if (j == 0) {
        float* o = partials + g * 8;
        #pragma unroll
        for (int q2 = 0; q2 < 5; ++q2)
            o[q2] = red[0][q2] + red[1][q2] + red[2][q2] + red[3][q2];
        o[5] = fmaxf(fmaxf(red[0][5], red[1][5]), fmaxf(red[2][5], red[3][5]));
    }
}

// Single-block final reduction: 512 records -> loss scalar.
// Per-image "any mask pixel" guard derived from the per-image st sum.
__global__ __launch_bounds__(256) void final_kernel(const float* __restrict__ partials,
                                                    float* __restrict__ out) {
    int t = threadIdx.x;
    // 32 records per image; thread t reads records 2t, 2t+1 (both image t>>4)
    float s0 = 0.f, s1 = 0.f, s2 = 0.f, s3 = 0.f, s4 = 0.f, m5 = 0.f;
    #pragma unroll
    for (int e = 0; e < 2; ++e) {
        const float* rec = partials + ((t * 2 + e) << 3);
        s0 += rec[0]; s1 += rec[1]; s2 += rec[2]; s3 += rec[3];
        s4 += rec[4];
        m5 = fmaxf(m5, rec[5]);
    }
    __shared__ float arr[256][3];
    arr[t][0] = s4; arr[t][1] = m5; arr[t][2] = s1;   // sphip, amax, st (per-image pieces)
    __syncthreads();
    __shared__ float bnd[16];
    if (t < 16) {
        float Sb = 0.f, Mb = 0.f, STb = 0.f;
        for (int e = 0; e < 16; ++e) {
            Sb += arr[t * 16 + e][0];
            Mb = fmaxf(Mb, arr[t * 16 + e][1]);
            STb += arr[t * 16 + e][2];
        }
        // jnp.any(mask>0) == (count of mask pixels > 0)
        bnd[t] = (STb > 0.0f) ? (Sb / (Mb + 1e-8f)) : 0.0f;
    }
    #pragma unroll
    for (int off = 32; off > 0; off >>= 1) {
        s0 += __shfl_down(s0, off, 64);
        s1 += __shfl_down(s1, off, 64);
        s2 += __shfl_down(s2, off, 64);
        s3 += __shfl_down(s3, off, 64);
    }
    __shared__ float wred[4][4];
    int lane = t & 63, wv = t >> 6;
    if (lane == 0) { wred[wv][0] = s0; wred[wv][1] = s1; wred[wv][2] = s2; wred[wv][3] = s3; }
    __syncthreads();
    if (t == 0) {
        float sp   = wred[0][0] + wred[1][0] + wred[2][0] + wred[3][0];
        float st   = wred[0][1] + wred[1][1] + wred[2][1] + wred[3][1];
        float spt  = wred[0][2] + wred[1][2] + wred[2][2] + wred[3][2];
        float sbce = wred[0][3] + wred[1][3] + wred[2][3] + wred[3][3];
        float sbnd = 0.f;
        #pragma unroll
        for (int bb2 = 0; bb2 < BB; ++bb2) sbnd += bnd[bb2];
        float dice = 1.0f - (2.0f * spt + 1e-6f) / (sp + st + 1e-6f);
        float invN = 1.0f / (float)NPIX;
        float boundary = sbnd * invN;
        float bce = sbce * invN;
        float alpha = 0.005f;
        float beta = 0.6f - alpha;      // 0.595
        out[0] = (1.0f - beta) * dice + beta * boundary + 0.4f * bce;
    }
}

extern "C" void kernel_launch(void* const* d_in, const int* in_sizes, int n_in,
                              void* d_out, int out_size, void* d_ws, size_t ws_size,
                              hipStream_t stream) {
    (void)in_sizes; (void)n_in; (void)out_size; (void)ws_size;
    const float* pred = (const float*)d_in[0];
    const float* targ = (const float*)d_in[1];
    unsigned short* zb = (unsigned short*)d_ws;   // 128 KB
    float* partials = (float*)((char*)d_ws + BB * CH * WW * sizeof(unsigned short));

    zbuild_kernel<<<BB * CH, 64, 0, stream>>>((const float4*)targ, (ushort4*)zb);
    rowmin_fused_kernel<<<NRB, 256, 0, stream>>>(zb, pred, partials);
    final_kernel<<<1, 256, 0, stream>>>(partials, (float*)d_out);
}